// Round 5
// baseline (84.486 us; speedup 1.0000x reference)
//
#include <hip/hip_runtime.h>
#include <hip/hip_bf16.h>

typedef __attribute__((ext_vector_type(8))) short bf16x8;
typedef __attribute__((ext_vector_type(4))) float f32x4;
typedef __attribute__((ext_vector_type(4))) unsigned short u16x4;
typedef __attribute__((ext_vector_type(4))) unsigned int u32x4;
typedef __attribute__((ext_vector_type(2))) unsigned int u32x2;

#define MFMA16(a, b, c) __builtin_amdgcn_mfma_f32_16x16x32_bf16((a), (b), (c), 0, 0, 0)

#define WQT_ELEMS 27648   // 288*96
#define WPT_ELEMS 9216    // 96*96

__device__ __forceinline__ unsigned short cvt_bf(float f) {
    __hip_bfloat16 h = __float2bfloat16(f);   // native RNE conversion
    return *reinterpret_cast<unsigned short*>(&h);
}
__device__ __forceinline__ unsigned pack2bf(float a, float b) {
    return (unsigned)cvt_bf(a) | ((unsigned)cvt_bf(b) << 16);
}

// Transpose+convert weights; q-columns (j<96) pre-scaled by (1/sqrt(24))*log2(e)
__global__ void wconv_kernel(const float* __restrict__ wqkv,
                             const float* __restrict__ wproj,
                             unsigned short* __restrict__ wsT) {
    int o = blockIdx.x * 256 + threadIdx.x;
    if (o < WQT_ELEMS) {
        int j = o / 96, c = o % 96;
        float w = wqkv[c * 288 + j];
        if (j < 96) w *= 0.2944889313f;
        wsT[o] = cvt_bf(w);
    } else if (o < WQT_ELEMS + WPT_ELEMS) {
        int o2 = o - WQT_ELEMS;
        int j = o2 / 96, c = o2 % 96;
        wsT[o] = cvt_bf(wproj[c * 96 + j]);
    }
}

// Packed-swizzled address for the unified x/q/O buffer: logical (t in [0,64), c in [0,96)).
// 3 chunks of 32 cols; 2 token-rows per 128B line; XOR swizzle on bits 4-6.
__device__ __forceinline__ int xq_addr(int t, int c) {
    return ((c >> 5) << 12) + ((t >> 1) << 7)
         + ((((t & 1) << 6) + ((c & 31) << 1)) ^ (((t >> 1) & 7) << 4));
}

// One block per window. 256 threads = 4 waves. Wave wv owns token rows [16wv,16wv+16).
// LDS = 40960 B -> 4 blocks/CU.
// All GEMMs computed operand-swapped (D = W*X etc.) so each lane's 4 D-values lie
// along consecutive CHANNELS of one token -> vectorized b64/b128 LDS stores.
__global__ __launch_bounds__(256, 4)
void winattn_kernel(const float* __restrict__ x,
                    const unsigned short* __restrict__ wsT,
                    const float* __restrict__ bproj,
                    float* __restrict__ out) {
    __shared__ __align__(16) char LDS[40960];
    char* xq  = LDS;              // 12288 B: x -> q -> O (packed-swizzled bf16)
    char* ksb = LDS + 12288;      // 16384 B: k [ktok][hd*32+kk], XOR-swizzled, kk 24..31 zero
    char* vtb = LDS + 28672;      // 12288 B: v^T [ch][tok], XOR-swizzled
    float* fbuf = reinterpret_cast<float*>(LDS + 12288);  // f32 proj out [64][stride 100]

    const int tid = threadIdx.x;
    const int lane = tid & 63;
    const int wv = tid >> 6;
    const int p  = lane & 15;
    const int qg = lane >> 4;

    const int iw  = blockIdx.x;
    const int l_i = iw & 31;
    const int m_i = (iw >> 5) & 15;
    const int n_i = iw >> 9;

    const f32x4 fzero = {0.f, 0.f, 0.f, 0.f};

    // QKV M-tile (out-channel tile) split: wv0: 0-4, wv1: 5-9, wv2: 10-13, wv3: 14-17
    const int ntile = (wv < 2) ? 5 : 4;
    const int tbase = (wv < 2) ? wv * 5 : 10 + (wv - 2) * 4;

    // ---------- phase 0: issue first W-tile prefetch (wsT independent of LDS) ----------
    bf16x8 bpre[3];
    #pragma unroll
    for (int kt = 0; kt < 3; ++kt)
        bpre[kt] = *reinterpret_cast<const bf16x8*>(&wsT[(tbase * 16 + p) * 96 + kt * 32 + qg * 8]);

    // ---------- phase 1: stage x window -> LDS (bf16, packed layout) ----------
    #pragma unroll
    for (int it = 0; it < 6; ++it) {
        int slot = tid + it * 256;            // 64 tokens * 24 float4 slots
        int t = slot / 24, cq = slot % 24;
        int td = t >> 4, th = (t >> 2) & 3, tw = t & 3;
        int off = (((n_i * 4 + td) * 64 + (m_i * 4 + th)) * 128 + (l_i * 4 + tw)) * 96 + cq * 4;
        float4 v4 = *reinterpret_cast<const float4*>(x + off);
        u16x4 h;
        h[0] = cvt_bf(v4.x); h[1] = cvt_bf(v4.y); h[2] = cvt_bf(v4.z); h[3] = cvt_bf(v4.w);
        *reinterpret_cast<u16x4*>(xq + xq_addr(t, cq * 4)) = h;
    }
    // zero k head-pads (kk 24..31 per head, swizzled addr)
    {
        int t = tid >> 2, hd = tid & 3;
        bf16x8 z = {0, 0, 0, 0, 0, 0, 0, 0};
        int cb = hd * 64 + 48;
        *reinterpret_cast<bf16x8*>(ksb + t * 256 + (cb ^ ((t & 7) << 4))) = z;
    }
    __syncthreads();

    // ---------- phase 2: QKV GEMM (swapped)  qkv^T[288][64] = wq^T[288][96] @ x^T[96][64] ----------
    // B-frags = x (same layout as the A-frags of the unswapped form)
    bf16x8 afr[4][3];
    #pragma unroll
    for (int nt = 0; nt < 4; ++nt)
        #pragma unroll
        for (int kt = 0; kt < 3; ++kt)
            afr[nt][kt] = *reinterpret_cast<const bf16x8*>(xq + xq_addr(nt * 16 + p, kt * 32 + qg * 8));
    __syncthreads();   // xq fully register-hoisted; q may now overwrite it

    #pragma unroll
    for (int i = 0; i < 5; ++i) {
        if (i >= ntile) break;                // wave-uniform
        int m = tbase + i;
        bf16x8 wcur[3] = {bpre[0], bpre[1], bpre[2]};
        if (i + 1 < ntile) {                  // lookahead prefetch
            #pragma unroll
            for (int kt = 0; kt < 3; ++kt)
                bpre[kt] = *reinterpret_cast<const bf16x8*>(&wsT[((m + 1) * 16 + p) * 96 + kt * 32 + qg * 8]);
        }
        f32x4 acc[4] = {fzero, fzero, fzero, fzero};
        #pragma unroll
        for (int kt = 0; kt < 3; ++kt)
            #pragma unroll
            for (int nt = 0; nt < 4; ++nt)
                acc[nt] = MFMA16(wcur[kt], afr[nt][kt], acc[nt]);
        // lane holds qkv[tok = nt*16+p][j = m*16 + 4qg + rg] -> channel-contiguous stores
        if (m < 6) {                          // q -> xq row-major [tok][ch], b64
            int ch = m * 16 + 4 * qg;
            #pragma unroll
            for (int nt = 0; nt < 4; ++nt) {
                u32x2 w = { pack2bf(acc[nt][0], acc[nt][1]), pack2bf(acc[nt][2], acc[nt][3]) };
                *reinterpret_cast<u32x2*>(xq + xq_addr(nt * 16 + p, ch)) = w;
            }
        } else if (m < 12) {                  // k -> ks row-major [ktok][hd*32+kk], b64
            int jk = (m - 6) * 16 + 4 * qg;   // 4-run stays within one head (jk%24 <= 20)
            int cb = jk * 2 + (jk / 24) * 16;
            #pragma unroll
            for (int nt = 0; nt < 4; ++nt) {
                int t = nt * 16 + p;
                u32x2 w = { pack2bf(acc[nt][0], acc[nt][1]), pack2bf(acc[nt][2], acc[nt][3]) };
                *reinterpret_cast<u32x2*>(ksb + t * 256 + (cb ^ ((t & 7) << 4))) = w;
            }
        } else {                              // v -> v^T [ch][tok], scalar (needs transpose)
            int jv = (m - 12) * 16 + 4 * qg;
            #pragma unroll
            for (int nt = 0; nt < 4; ++nt) {
                int t2 = (nt * 16 + p) * 2;
                #pragma unroll
                for (int rg = 0; rg < 4; ++rg) {
                    int row = jv + rg;
                    *reinterpret_cast<unsigned short*>(vtb + row * 128 + (t2 ^ ((row & 7) << 4))) = cvt_bf(acc[nt][rg]);
                }
            }
        }
    }
    __syncthreads();

    // ---------- phase 3: attention, swapped QK^T -> register softmax -> swapped PV ----------
    #pragma unroll 1
    for (int hd = 0; hd < 4; ++hd) {
        // S^T = mfma(K, Q): D[col=q-token(p), row=k-token(qg*4+rg)+16nt]
        bf16x8 aqh = *reinterpret_cast<const bf16x8*>(xq + xq_addr(wv * 16 + p, hd * 24 + qg * 8));
        f32x4 sacc[4];
        #pragma unroll
        for (int nt = 0; nt < 4; ++nt) {
            int t = nt * 16 + p;
            bf16x8 ak = *reinterpret_cast<const bf16x8*>(ksb + t * 256 + ((hd * 64 + qg * 16) ^ ((t & 7) << 4)));
            sacc[nt] = MFMA16(ak, aqh, fzero);
        }
        // lane (p,qg) holds S[k = 16nt+4qg+rg][q = wv*16+p] (already *scale*log2e)
        float mm = sacc[0][0];
        #pragma unroll
        for (int nt = 0; nt < 4; ++nt)
            #pragma unroll
            for (int rg = 0; rg < 4; ++rg)
                mm = fmaxf(mm, sacc[nt][rg]);
        mm = fmaxf(mm, __shfl_xor(mm, 16));
        mm = fmaxf(mm, __shfl_xor(mm, 32));
        float pw[4][4];
        float sum = 0.f;
        #pragma unroll
        for (int nt = 0; nt < 4; ++nt)
            #pragma unroll
            for (int rg = 0; rg < 4; ++rg) {
                float e = exp2f(sacc[nt][rg] - mm);
                pw[nt][rg] = e;
                sum += e;
            }
        sum += __shfl_xor(sum, 16);
        sum += __shfl_xor(sum, 32);
        float inv = 1.0f / sum;
        unsigned pk[4][2];
        #pragma unroll
        for (int nt = 0; nt < 4; ++nt) {
            pk[nt][0] = pack2bf(pw[nt][0] * inv, pw[nt][1] * inv);
            pk[nt][1] = pack2bf(pw[nt][2] * inv, pw[nt][3] * inv);
        }
        // redistribute so lane (p,qg) holds P[qtok=p][ktok = kt*32 + qg*8 + j]
        u32x4 pa0, pa1;
        #pragma unroll
        for (int d = 0; d < 4; ++d) {
            int src = ((qg & 1) * 2 + (d >> 1)) * 16 + p;
            int lo0 = __shfl((int)pk[0][d & 1], src);
            int hi0 = __shfl((int)pk[1][d & 1], src);
            int lo1 = __shfl((int)pk[2][d & 1], src);
            int hi1 = __shfl((int)pk[3][d & 1], src);
            pa0[d] = (qg < 2) ? (unsigned)lo0 : (unsigned)hi0;
            pa1[d] = (qg < 2) ? (unsigned)lo1 : (unsigned)hi1;
        }
        bf16x8 a0 = __builtin_bit_cast(bf16x8, pa0);
        bf16x8 a1 = __builtin_bit_cast(bf16x8, pa1);
        // O^T = mfma(V^T, P^T): same vT reads as before, P-frags now the B-operand
        f32x4 oacc[2] = {fzero, fzero};
        #pragma unroll
        for (int n2 = 0; n2 < 2; ++n2) {
            int vr = hd * 24 + n2 * 16 + p;
            vr = vr > 95 ? 95 : vr;           // clamped garbage rows land in discarded D rows
            int rb = vr * 128, sw = (vr & 7) << 4;
            bf16x8 av0 = *reinterpret_cast<const bf16x8*>(vtb + rb + ((qg * 16) ^ sw));
            bf16x8 av1 = *reinterpret_cast<const bf16x8*>(vtb + rb + ((64 + qg * 16) ^ sw));
            oacc[n2] = MFMA16(av0, a0, oacc[n2]);
            oacc[n2] = MFMA16(av1, a1, oacc[n2]);
        }
        // lane holds O[tok = wv*16+p][ch = hd*24 + n2*16 + 4qg + rg] -> b64 stores
        {
            u32x2 w0 = { pack2bf(oacc[0][0], oacc[0][1]), pack2bf(oacc[0][2], oacc[0][3]) };
            *reinterpret_cast<u32x2*>(xq + xq_addr(wv * 16 + p, hd * 24 + 4 * qg)) = w0;
            if (qg < 2) {
                u32x2 w1 = { pack2bf(oacc[1][0], oacc[1][1]), pack2bf(oacc[1][2], oacc[1][3]) };
                *reinterpret_cast<u32x2*>(xq + xq_addr(wv * 16 + p, hd * 24 + 16 + 4 * qg)) = w1;
            }
        }
    }

    // ---------- phase 4: proj (swapped) + bias -> f32 LDS (own rows only) ----------
    bf16x8 ofr[3];
    #pragma unroll
    for (int kt = 0; kt < 3; ++kt)
        ofr[kt] = *reinterpret_cast<const bf16x8*>(xq + xq_addr(wv * 16 + p, kt * 32 + qg * 8));
    __syncthreads();   // all waves done with ksb/vtb before fbuf overlays them

    const unsigned short* wpT = wsT + WQT_ELEMS;
    bf16x8 wpre[3];
    #pragma unroll
    for (int kt = 0; kt < 3; ++kt)
        wpre[kt] = *reinterpret_cast<const bf16x8*>(&wpT[p * 96 + kt * 32 + qg * 8]);
    #pragma unroll
    for (int m = 0; m < 6; ++m) {
        bf16x8 wcur[3] = {wpre[0], wpre[1], wpre[2]};
        if (m < 5) {
            #pragma unroll
            for (int kt = 0; kt < 3; ++kt)
                wpre[kt] = *reinterpret_cast<const bf16x8*>(&wpT[((m + 1) * 16 + p) * 96 + kt * 32 + qg * 8]);
        }
        f32x4 acc = fzero;
        #pragma unroll
        for (int kt = 0; kt < 3; ++kt)
            acc = MFMA16(wcur[kt], ofr[kt], acc);
        // lane holds out[tok = wv*16+p][ch = m*16 + 4qg + rg]
        float4 bb = *reinterpret_cast<const float4*>(bproj + m * 16 + 4 * qg);
        f32x4 r;
        r[0] = acc[0] + bb.x; r[1] = acc[1] + bb.y;
        r[2] = acc[2] + bb.z; r[3] = acc[3] + bb.w;
        *reinterpret_cast<f32x4*>(fbuf + (wv * 16 + p) * 100 + m * 16 + 4 * qg) = r;
    }
    __syncthreads();

    // ---------- phase 5: cooperative fully-coalesced f32 store (mirrors phase 1) ----------
    #pragma unroll
    for (int it = 0; it < 6; ++it) {
        int slot = tid + it * 256;
        int t = slot / 24, cq = slot % 24;
        int td = t >> 4, th = (t >> 2) & 3, tw = t & 3;
        int off = (((n_i * 4 + td) * 64 + (m_i * 4 + th)) * 128 + (l_i * 4 + tw)) * 96 + cq * 4;
        float4 v4 = *reinterpret_cast<const float4*>(fbuf + t * 100 + cq * 4);
        *reinterpret_cast<float4*>(out + off) = v4;
    }
}

extern "C" void kernel_launch(void* const* d_in, const int* in_sizes, int n_in,
                              void* d_out, int out_size, void* d_ws, size_t ws_size,
                              hipStream_t stream) {
    const float* x     = (const float*)d_in[0];
    const float* wqkv  = (const float*)d_in[1];
    const float* wproj = (const float*)d_in[2];
    const float* bproj = (const float*)d_in[3];
    float* out = (float*)d_out;
    unsigned short* wsT = (unsigned short*)d_ws;

    wconv_kernel<<<dim3((WQT_ELEMS + WPT_ELEMS) / 256), dim3(256), 0, stream>>>(wqkv, wproj, wsT);
    winattn_kernel<<<dim3(4096), dim3(256), 0, stream>>>(x, wsT, bproj, out);
}

// Round 6
// 83.016 us; speedup vs baseline: 1.0177x; 1.0177x over previous
//
#include <hip/hip_runtime.h>
#include <hip/hip_bf16.h>

typedef __attribute__((ext_vector_type(8))) short bf16x8;
typedef __attribute__((ext_vector_type(4))) float f32x4;
typedef __attribute__((ext_vector_type(4))) unsigned short u16x4;
typedef __attribute__((ext_vector_type(4))) unsigned int u32x4;
typedef __attribute__((ext_vector_type(2))) unsigned int u32x2;

#define MFMA16(a, b, c) __builtin_amdgcn_mfma_f32_16x16x32_bf16((a), (b), (c), 0, 0, 0)

#define WQT_ELEMS 27648   // 288*96
#define WPT_ELEMS 9216    // 96*96

__device__ __forceinline__ unsigned short cvt_bf(float f) {
    __hip_bfloat16 h = __float2bfloat16(f);   // native RNE conversion
    return *reinterpret_cast<unsigned short*>(&h);
}
__device__ __forceinline__ unsigned pack2bf(float a, float b) {
    return (unsigned)cvt_bf(a) | ((unsigned)cvt_bf(b) << 16);
}

// Transpose+convert weights; q-columns (j<96) pre-scaled by (1/sqrt(24))*log2(e)
__global__ void wconv_kernel(const float* __restrict__ wqkv,
                             const float* __restrict__ wproj,
                             unsigned short* __restrict__ wsT) {
    int o = blockIdx.x * 256 + threadIdx.x;
    if (o < WQT_ELEMS) {
        int j = o / 96, c = o % 96;
        float w = wqkv[c * 288 + j];
        if (j < 96) w *= 0.2944889313f;
        wsT[o] = cvt_bf(w);
    } else if (o < WQT_ELEMS + WPT_ELEMS) {
        int o2 = o - WQT_ELEMS;
        int j = o2 / 96, c = o2 % 96;
        wsT[o] = cvt_bf(wproj[c * 96 + j]);
    }
}

// Packed-swizzled address for the unified x/q/O buffer: logical (t in [0,64), c in [0,96)).
// 3 chunks of 32 cols; 2 token-rows per 128B line; XOR swizzle on bits 4-6.
__device__ __forceinline__ int xq_addr(int t, int c) {
    return ((c >> 5) << 12) + ((t >> 1) << 7)
         + ((((t & 1) << 6) + ((c & 31) << 1)) ^ (((t >> 1) & 7) << 4));
}

// One block per window. 256 threads = 4 waves. Wave wv owns token rows [16wv,16wv+16).
// LDS = 40960 B -> 4 blocks/CU. All GEMMs operand-swapped (channel-contiguous D rows).
// Phase 2 is fully static per wave: literal tile indices, compile-time store kind.
__global__ __launch_bounds__(256, 4)
void winattn_kernel(const float* __restrict__ x,
                    const unsigned short* __restrict__ wsT,
                    const float* __restrict__ bproj,
                    float* __restrict__ out) {
    __shared__ __align__(16) char LDS[40960];
    char* xq  = LDS;              // 12288 B: x -> q -> O (packed-swizzled bf16)
    char* ksb = LDS + 12288;      // 16384 B: k [ktok][hd*32+kk], XOR-swizzled, kk 24..31 zero
    char* vtb = LDS + 28672;      // 12288 B: v^T [ch][tok], XOR-swizzled
    float* fbuf = reinterpret_cast<float*>(LDS + 12288);  // f32 proj out [64][stride 100]

    const int tid = threadIdx.x;
    const int lane = tid & 63;
    const int wv = tid >> 6;
    const int p  = lane & 15;
    const int qg = lane >> 4;

    const int iw  = blockIdx.x;
    const int l_i = iw & 31;
    const int m_i = (iw >> 5) & 15;
    const int n_i = iw >> 9;

    const f32x4 fzero = {0.f, 0.f, 0.f, 0.f};

    bf16x8 afr[4][3];   // x fragments (B-operand of swapped QKV GEMM)

    auto load_w = [&](int m, bf16x8* wc) {
        #pragma unroll
        for (int kt = 0; kt < 3; ++kt)
            wc[kt] = *reinterpret_cast<const bf16x8*>(&wsT[(m * 16 + p) * 96 + kt * 32 + qg * 8]);
    };
    auto mfma_tile = [&](const bf16x8* wc, f32x4* acc) {
        #pragma unroll
        for (int kt = 0; kt < 3; ++kt)
            #pragma unroll
            for (int nt = 0; nt < 4; ++nt)
                acc[nt] = MFMA16(wc[kt], afr[nt][kt], acc[nt]);
    };
    // lane holds qkv[tok = nt*16+p][j = m*16 + 4qg + rg]; m is a literal at every call site.
    auto do_q = [&](int m, const bf16x8* wc) {
        f32x4 acc[4] = {fzero, fzero, fzero, fzero};
        mfma_tile(wc, acc);
        int ch = m * 16 + 4 * qg;
        #pragma unroll
        for (int nt = 0; nt < 4; ++nt) {
            u32x2 w = { pack2bf(acc[nt][0], acc[nt][1]), pack2bf(acc[nt][2], acc[nt][3]) };
            *reinterpret_cast<u32x2*>(xq + xq_addr(nt * 16 + p, ch)) = w;
        }
    };
    auto do_k = [&](int m, const bf16x8* wc) {
        f32x4 acc[4] = {fzero, fzero, fzero, fzero};
        mfma_tile(wc, acc);
        int jk = (m - 6) * 16 + 4 * qg;       // 4-run stays within one head
        int cb = jk * 2 + (jk / 24) * 16;
        #pragma unroll
        for (int nt = 0; nt < 4; ++nt) {
            int t = nt * 16 + p;
            u32x2 w = { pack2bf(acc[nt][0], acc[nt][1]), pack2bf(acc[nt][2], acc[nt][3]) };
            *reinterpret_cast<u32x2*>(ksb + t * 256 + (cb ^ ((t & 7) << 4))) = w;
        }
    };
    auto do_v = [&](int m, const bf16x8* wc) {
        f32x4 acc[4] = {fzero, fzero, fzero, fzero};
        mfma_tile(wc, acc);
        int jv = (m - 12) * 16 + 4 * qg;
        #pragma unroll
        for (int nt = 0; nt < 4; ++nt) {
            int t2 = (nt * 16 + p) * 2;
            #pragma unroll
            for (int rg = 0; rg < 4; ++rg) {
                int row = jv + rg;
                *reinterpret_cast<unsigned short*>(vtb + row * 128 + (t2 ^ ((row & 7) << 4))) = cvt_bf(acc[nt][rg]);
            }
        }
    };

    // ---------- phase 0: prefetch this wave's first W-tile (wsT independent of LDS) ----------
    bf16x8 wA[3], wB[3];
    const int tb0 = (wv < 2) ? wv * 5 : 10 + (wv - 2) * 4;
    load_w(tb0, wA);

    // ---------- phase 1: stage x window -> LDS (bf16, packed layout) ----------
    #pragma unroll
    for (int it = 0; it < 6; ++it) {
        int slot = tid + it * 256;            // 64 tokens * 24 float4 slots
        int t = slot / 24, cq = slot % 24;
        int td = t >> 4, th = (t >> 2) & 3, tw = t & 3;
        int off = (((n_i * 4 + td) * 64 + (m_i * 4 + th)) * 128 + (l_i * 4 + tw)) * 96 + cq * 4;
        float4 v4 = *reinterpret_cast<const float4*>(x + off);
        u16x4 h;
        h[0] = cvt_bf(v4.x); h[1] = cvt_bf(v4.y); h[2] = cvt_bf(v4.z); h[3] = cvt_bf(v4.w);
        *reinterpret_cast<u16x4*>(xq + xq_addr(t, cq * 4)) = h;
    }
    // zero k head-pads (kk 24..31 per head, swizzled addr)
    {
        int t = tid >> 2, hd = tid & 3;
        bf16x8 z = {0, 0, 0, 0, 0, 0, 0, 0};
        int cb = hd * 64 + 48;
        *reinterpret_cast<bf16x8*>(ksb + t * 256 + (cb ^ ((t & 7) << 4))) = z;
    }
    __syncthreads();

    // ---------- phase 2: QKV GEMM (swapped)  qkv^T[288][64] = wq^T[288][96] @ x^T[96][64] ----------
    #pragma unroll
    for (int nt = 0; nt < 4; ++nt)
        #pragma unroll
        for (int kt = 0; kt < 3; ++kt)
            afr[nt][kt] = *reinterpret_cast<const bf16x8*>(xq + xq_addr(nt * 16 + p, kt * 32 + qg * 8));
    __syncthreads();   // xq fully register-hoisted; q may now overwrite it

    // Straight-line per-wave tile schedule; all tile indices literal, store kind static.
    if (wv == 0) {          // tiles 0-4: all q
        load_w(1, wB); do_q(0, wA);
        load_w(2, wA); do_q(1, wB);
        load_w(3, wB); do_q(2, wA);
        load_w(4, wA); do_q(3, wB);
        do_q(4, wA);
    } else if (wv == 1) {   // tiles 5-9: q, then k
        load_w(6, wB); do_q(5, wA);
        load_w(7, wA); do_k(6, wB);
        load_w(8, wB); do_k(7, wA);
        load_w(9, wA); do_k(8, wB);
        do_k(9, wA);
    } else if (wv == 2) {   // tiles 10-13: k, k, v, v
        load_w(11, wB); do_k(10, wA);
        load_w(12, wA); do_k(11, wB);
        load_w(13, wB); do_v(12, wA);
        do_v(13, wB);
    } else {                // tiles 14-17: all v
        load_w(15, wB); do_v(14, wA);
        load_w(16, wA); do_v(15, wB);
        load_w(17, wB); do_v(16, wA);
        do_v(17, wB);
    }
    __syncthreads();

    // ---------- phase 3: attention, swapped QK^T -> register softmax -> swapped PV ----------
    #pragma unroll 1
    for (int hd = 0; hd < 4; ++hd) {
        // S^T = mfma(K, Q): D[col=q-token(p), row=k-token(qg*4+rg)+16nt]
        bf16x8 aqh = *reinterpret_cast<const bf16x8*>(xq + xq_addr(wv * 16 + p, hd * 24 + qg * 8));
        f32x4 sacc[4];
        #pragma unroll
        for (int nt = 0; nt < 4; ++nt) {
            int t = nt * 16 + p;
            bf16x8 ak = *reinterpret_cast<const bf16x8*>(ksb + t * 256 + ((hd * 64 + qg * 16) ^ ((t & 7) << 4)));
            sacc[nt] = MFMA16(ak, aqh, fzero);
        }
        // lane (p,qg) holds S[k = 16nt+4qg+rg][q = wv*16+p] (already *scale*log2e)
        float mm = sacc[0][0];
        #pragma unroll
        for (int nt = 0; nt < 4; ++nt)
            #pragma unroll
            for (int rg = 0; rg < 4; ++rg)
                mm = fmaxf(mm, sacc[nt][rg]);
        mm = fmaxf(mm, __shfl_xor(mm, 16));
        mm = fmaxf(mm, __shfl_xor(mm, 32));
        float pw[4][4];
        float sum = 0.f;
        #pragma unroll
        for (int nt = 0; nt < 4; ++nt)
            #pragma unroll
            for (int rg = 0; rg < 4; ++rg) {
                float e = exp2f(sacc[nt][rg] - mm);
                pw[nt][rg] = e;
                sum += e;
            }
        sum += __shfl_xor(sum, 16);
        sum += __shfl_xor(sum, 32);
        float inv = 1.0f / sum;
        unsigned pk[4][2];
        #pragma unroll
        for (int nt = 0; nt < 4; ++nt) {
            pk[nt][0] = pack2bf(pw[nt][0] * inv, pw[nt][1] * inv);
            pk[nt][1] = pack2bf(pw[nt][2] * inv, pw[nt][3] * inv);
        }
        // redistribute so lane (p,qg) holds P[qtok=p][ktok = kt*32 + qg*8 + j]
        u32x4 pa0, pa1;
        #pragma unroll
        for (int d = 0; d < 4; ++d) {
            int src = ((qg & 1) * 2 + (d >> 1)) * 16 + p;
            int lo0 = __shfl((int)pk[0][d & 1], src);
            int hi0 = __shfl((int)pk[1][d & 1], src);
            int lo1 = __shfl((int)pk[2][d & 1], src);
            int hi1 = __shfl((int)pk[3][d & 1], src);
            pa0[d] = (qg < 2) ? (unsigned)lo0 : (unsigned)hi0;
            pa1[d] = (qg < 2) ? (unsigned)lo1 : (unsigned)hi1;
        }
        bf16x8 a0 = __builtin_bit_cast(bf16x8, pa0);
        bf16x8 a1 = __builtin_bit_cast(bf16x8, pa1);
        // O^T = mfma(V^T, P^T)
        f32x4 oacc[2] = {fzero, fzero};
        #pragma unroll
        for (int n2 = 0; n2 < 2; ++n2) {
            int vr = hd * 24 + n2 * 16 + p;
            vr = vr > 95 ? 95 : vr;           // clamped garbage rows land in discarded D rows
            int rb = vr * 128, sw = (vr & 7) << 4;
            bf16x8 av0 = *reinterpret_cast<const bf16x8*>(vtb + rb + ((qg * 16) ^ sw));
            bf16x8 av1 = *reinterpret_cast<const bf16x8*>(vtb + rb + ((64 + qg * 16) ^ sw));
            oacc[n2] = MFMA16(av0, a0, oacc[n2]);
            oacc[n2] = MFMA16(av1, a1, oacc[n2]);
        }
        // lane holds O[tok = wv*16+p][ch = hd*24 + n2*16 + 4qg + rg] -> b64 stores
        {
            u32x2 w0 = { pack2bf(oacc[0][0], oacc[0][1]), pack2bf(oacc[0][2], oacc[0][3]) };
            *reinterpret_cast<u32x2*>(xq + xq_addr(wv * 16 + p, hd * 24 + 4 * qg)) = w0;
            if (qg < 2) {
                u32x2 w1 = { pack2bf(oacc[1][0], oacc[1][1]), pack2bf(oacc[1][2], oacc[1][3]) };
                *reinterpret_cast<u32x2*>(xq + xq_addr(wv * 16 + p, hd * 24 + 16 + 4 * qg)) = w1;
            }
        }
    }

    // ---------- phase 4: proj (swapped) + bias -> f32 LDS (own rows only) ----------
    bf16x8 ofr[3];
    #pragma unroll
    for (int kt = 0; kt < 3; ++kt)
        ofr[kt] = *reinterpret_cast<const bf16x8*>(xq + xq_addr(wv * 16 + p, kt * 32 + qg * 8));
    __syncthreads();   // all waves done with ksb/vtb before fbuf overlays them

    const unsigned short* wpT = wsT + WQT_ELEMS;
    bf16x8 wpre[3];
    #pragma unroll
    for (int kt = 0; kt < 3; ++kt)
        wpre[kt] = *reinterpret_cast<const bf16x8*>(&wpT[p * 96 + kt * 32 + qg * 8]);
    #pragma unroll
    for (int m = 0; m < 6; ++m) {
        bf16x8 wcur[3] = {wpre[0], wpre[1], wpre[2]};
        if (m < 5) {
            #pragma unroll
            for (int kt = 0; kt < 3; ++kt)
                wpre[kt] = *reinterpret_cast<const bf16x8*>(&wpT[((m + 1) * 16 + p) * 96 + kt * 32 + qg * 8]);
        }
        f32x4 acc = fzero;
        #pragma unroll
        for (int kt = 0; kt < 3; ++kt)
            acc = MFMA16(wcur[kt], ofr[kt], acc);
        // lane holds out[tok = wv*16+p][ch = m*16 + 4qg + rg]
        float4 bb = *reinterpret_cast<const float4*>(bproj + m * 16 + 4 * qg);
        f32x4 r;
        r[0] = acc[0] + bb.x; r[1] = acc[1] + bb.y;
        r[2] = acc[2] + bb.z; r[3] = acc[3] + bb.w;
        *reinterpret_cast<f32x4*>(fbuf + (wv * 16 + p) * 100 + m * 16 + 4 * qg) = r;
    }
    __syncthreads();

    // ---------- phase 5: cooperative coalesced NT f32 store (protects x's L3 residency) ----------
    #pragma unroll
    for (int it = 0; it < 6; ++it) {
        int slot = tid + it * 256;
        int t = slot / 24, cq = slot % 24;
        int td = t >> 4, th = (t >> 2) & 3, tw = t & 3;
        int off = (((n_i * 4 + td) * 64 + (m_i * 4 + th)) * 128 + (l_i * 4 + tw)) * 96 + cq * 4;
        f32x4 v4 = *reinterpret_cast<const f32x4*>(fbuf + t * 100 + cq * 4);
        __builtin_nontemporal_store(v4, reinterpret_cast<f32x4*>(out + off));
    }
}

extern "C" void kernel_launch(void* const* d_in, const int* in_sizes, int n_in,
                              void* d_out, int out_size, void* d_ws, size_t ws_size,
                              hipStream_t stream) {
    const float* x     = (const float*)d_in[0];
    const float* wqkv  = (const float*)d_in[1];
    const float* wproj = (const float*)d_in[2];
    const float* bproj = (const float*)d_in[3];
    float* out = (float*)d_out;
    unsigned short* wsT = (unsigned short*)d_ws;

    wconv_kernel<<<dim3((WQT_ELEMS + WPT_ELEMS) / 256), dim3(256), 0, stream>>>(wqkv, wproj, wsT);
    winattn_kernel<<<dim3(4096), dim3(256), 0, stream>>>(x, wsT, bproj, out);
}